// Round 11
// baseline (246.805 us; speedup 1.0000x reference)
//
#include <hip/hip_runtime.h>

// All tensors float32. Math structure exploited:
//  - softmax over axis of size 1 == 1.0 -> attn all-ones, Wa/ba dead.
//  - weighted = row-sum of tanh(agg), broadcast over COLUMNS (N==D quirk).
//  - lig_p = nf@Wl.T + const  ->  x0[h,i,j] = PL[i,h] + PR[j,h] + c[h]
//  - conv1 is LINEAR in rank-structured x0: y1_pre = U[xc][y] + V[yc][x] + K'.
//    conv kernel stages ys = relu(U+V+K'); conv2+conv3 on f16 MFMA.
//  - ROUND-11: launch-count 5 -> 3 (~40us was inter-launch serialization):
//    proj fused into gnn grid (by>=16 blocks); cveck+uv+w2pack merged;
//    conv wB staging = plain uint4 copy of prepacked w2 (div/f2h deleted).

typedef _Float16 half8 __attribute__((ext_vector_type(8)));
typedef _Float16 half4 __attribute__((ext_vector_type(4)));
typedef float    f32x4 __attribute__((ext_vector_type(4)));

__device__ __forceinline__ short f2h_bits(float f){
    _Float16 h = (_Float16)f;          // RNE
    return __builtin_bit_cast(short, h);
}
__device__ __forceinline__ half8 pack2(const float4& x, const float4& y){
    half8 r;
    r[0] = (_Float16)x.x; r[1] = (_Float16)x.y;
    r[2] = (_Float16)x.z; r[3] = (_Float16)x.w;
    r[4] = (_Float16)y.x; r[5] = (_Float16)y.y;
    r[6] = (_Float16)y.z; r[7] = (_Float16)y.w;
    return r;
}
__device__ __forceinline__ float tanh_fast(float x){
    float e = __expf(2.f * x);
    return 1.f - 2.f / (e + 1.f);
}

// ci-block swizzle for conv LDS tiles (round-4 verified layout)
#define SWZ(c) ((((c) >> 1) & 3) << 3)

// ---------------------------------------------------------------------------
// K1: gnn (MFMA, register prefetch) + proj fused via grid role split.
// grid (8, 20, 2), 512 thr. by<16: gnn tile BM=128/BN=64/BK=64.
// by>=16: proj -- PL[i,h]=dot(nf[i,:],Wl[h,:]), 32 rows per block.
// ---------------------------------------------------------------------------
__global__ __launch_bounds__(512) void gnnproj_kernel(
    const float* __restrict__ lig_nf, const float* __restrict__ lig_ef,
    const float* __restrict__ rec_nf, const float* __restrict__ rec_ef,
    const float* __restrict__ Wn, const float* __restrict__ We,
    const float* __restrict__ bn, const float* __restrict__ be,
    const float* __restrict__ W_hopi,
    float* __restrict__ part,   // [2][16][1024]
    float* __restrict__ PL, float* __restrict__ PR)
{
    __shared__ __attribute__((aligned(16))) short As[128 * 64];
    __shared__ __attribute__((aligned(16))) short Bs[64 * 64];
    __shared__ float red[128][2];

    const int t  = threadIdx.x;
    const int cx = blockIdx.z;

    if (blockIdx.y >= 16){
        // ---------------- proj role: 32 rows x 32 h per block -------------
        const int pz = blockIdx.y - 16;          // 0..3
        const float* nf = cx ? rec_nf : lig_nf;
        const float* W  = W_hopi + (cx ? 1024 : 0);
        float* outp     = cx ? PR : PL;
        const int h  = t & 31;
        const int r0 = t >> 5;                   // 0..15
        const float* wrow = W + (size_t)h * 2048;
        #pragma unroll
        for (int half = 0; half < 2; ++half){
            int i = blockIdx.x * 128 + pz * 32 + r0 + half * 16;
            const float* nrow = nf + (size_t)i * 1024;
            float s0 = 0.f, s1 = 0.f;
            #pragma unroll 4
            for (int j = 0; j < 1024; j += 8){
                float4 a0 = *reinterpret_cast<const float4*>(nrow + j);
                float4 b0 = *reinterpret_cast<const float4*>(wrow + j);
                float4 a1 = *reinterpret_cast<const float4*>(nrow + j + 4);
                float4 b1 = *reinterpret_cast<const float4*>(wrow + j + 4);
                s0 = fmaf(a0.x, b0.x, s0); s0 = fmaf(a0.y, b0.y, s0);
                s0 = fmaf(a0.z, b0.z, s0); s0 = fmaf(a0.w, b0.w, s0);
                s1 = fmaf(a1.x, b1.x, s1); s1 = fmaf(a1.y, b1.y, s1);
                s1 = fmaf(a1.z, b1.z, s1); s1 = fmaf(a1.w, b1.w, s1);
            }
            outp[(size_t)i * 32 + h] = s0 + s1;
        }
        return;
    }

    // ---------------- gnn role (round-8 verbatim) -------------------------
    const float* A0 = cx ? rec_nf : lig_nf;
    const float* A1 = cx ? rec_ef : lig_ef;
    const int j0 = blockIdx.x * 128;
    const int d0 = blockIdx.y * 64;

    const int wid  = t >> 6;
    const int wm   = wid >> 1;
    const int wn   = wid & 1;
    const int lane = t & 63;
    const int lr   = lane & 15;
    const int lg   = lane >> 4;

    f32x4 acc[2][2];
    #pragma unroll
    for (int m = 0; m < 2; ++m)
        #pragma unroll
        for (int n = 0; n < 2; ++n)
            acc[m][n] = (f32x4){0.f, 0.f, 0.f, 0.f};

    const int arow = t >> 2;
    const int akc  = (t & 3) * 16;
    const int brow = t >> 3;
    const int bkc  = (t & 7) * 8;

    float4 av[4], bv[2];
    {
        const float* ap = A0 + (size_t)(j0 + arow) * 1024 + akc;
        const float* bp = Wn + (size_t)(d0 + brow) * 1024 + bkc;
        #pragma unroll
        for (int q = 0; q < 4; ++q) av[q] = *reinterpret_cast<const float4*>(ap + q * 4);
        #pragma unroll
        for (int q = 0; q < 2; ++q) bv[q] = *reinterpret_cast<const float4*>(bp + q * 4);
    }

    for (int kb = 0; kb < 2048; kb += 64){
        __syncthreads();
        {
            const int ga = (t & 3) * 2;
            const int sa = arow & 7;
            *reinterpret_cast<half8*>(&As[arow * 64 + ((ga    ) ^ sa) * 8]) = pack2(av[0], av[1]);
            *reinterpret_cast<half8*>(&As[arow * 64 + ((ga + 1) ^ sa) * 8]) = pack2(av[2], av[3]);
            *reinterpret_cast<half8*>(&Bs[brow * 64 + (((t & 7)) ^ (brow & 7)) * 8]) = pack2(bv[0], bv[1]);
        }
        {
            const int kbn = (kb + 64) & 2047;
            const float* Asrc = (kbn < 1024) ? A0 : A1;
            const float* Bsrc = (kbn < 1024) ? Wn : We;
            const int kk = kbn & 1023;
            const float* ap = Asrc + (size_t)(j0 + arow) * 1024 + kk + akc;
            const float* bp = Bsrc + (size_t)(d0 + brow) * 1024 + kk + bkc;
            #pragma unroll
            for (int q = 0; q < 4; ++q) av[q] = *reinterpret_cast<const float4*>(ap + q * 4);
            #pragma unroll
            for (int q = 0; q < 2; ++q) bv[q] = *reinterpret_cast<const float4*>(bp + q * 4);
        }
        __syncthreads();

        #pragma unroll
        for (int ks = 0; ks < 2; ++ks){
            half8 Af[2], Bf[2];
            #pragma unroll
            for (int m = 0; m < 2; ++m){
                int row = wm * 32 + m * 16 + lr;
                int g   = ((ks * 4 + lg) ^ (row & 7)) * 8;
                Af[m] = *reinterpret_cast<const half8*>(&As[row * 64 + g]);
            }
            #pragma unroll
            for (int n = 0; n < 2; ++n){
                int col = wn * 32 + n * 16 + lr;
                int g   = ((ks * 4 + lg) ^ (col & 7)) * 8;
                Bf[n] = *reinterpret_cast<const half8*>(&Bs[col * 64 + g]);
            }
            #pragma unroll
            for (int m = 0; m < 2; ++m)
                #pragma unroll
                for (int n = 0; n < 2; ++n)
                    acc[m][n] = __builtin_amdgcn_mfma_f32_16x16x32_f16(
                        Af[m], Bf[n], acc[m][n], 0, 0, 0);
        }
    }

    float rowsum[2][4];
    #pragma unroll
    for (int m = 0; m < 2; ++m)
        #pragma unroll
        for (int jj = 0; jj < 4; ++jj) rowsum[m][jj] = 0.f;
    #pragma unroll
    for (int n = 0; n < 2; ++n){
        int d = d0 + wn * 32 + n * 16 + lr;
        float bias = bn[d] + be[d];
        #pragma unroll
        for (int m = 0; m < 2; ++m)
            #pragma unroll
            for (int jj = 0; jj < 4; ++jj)
                rowsum[m][jj] += tanh_fast(acc[m][n][jj] + bias);
    }
    #pragma unroll
    for (int mask = 1; mask < 16; mask <<= 1)
        #pragma unroll
        for (int m = 0; m < 2; ++m)
            #pragma unroll
            for (int jj = 0; jj < 4; ++jj)
                rowsum[m][jj] += __shfl_xor(rowsum[m][jj], mask);
    __syncthreads();
    if (lr == 0){
        #pragma unroll
        for (int m = 0; m < 2; ++m)
            #pragma unroll
            for (int jj = 0; jj < 4; ++jj)
                red[wm * 32 + m * 16 + lg * 4 + jj][wn] = rowsum[m][jj];
    }
    __syncthreads();
    if (t < 128)
        part[(size_t)cx * 16384 + (size_t)blockIdx.y * 1024 + j0 + t]
            = red[t][0] + red[t][1];
}

// ---------------------------------------------------------------------------
// K2: merged prep. grid 98 x 256 thr.
//  blocks 0..95 : uv  (yb = b&15, cs = (b>>4)%3, uvz = b/48)
//  block  96    : cveck (w1 staged in LDS, unrolled taps)
//  block  97    : w2pack -> f16 swizzled image for conv's LDS copy
// ---------------------------------------------------------------------------
__global__ __launch_bounds__(256) void prep_kernel(
    const float* __restrict__ W_hopi, const float* __restrict__ b_hopi,
    const float* __restrict__ w1, const float* __restrict__ b1,
    const float* __restrict__ w2,
    const float* __restrict__ part,
    const float* __restrict__ PL, const float* __restrict__ PR,
    float* __restrict__ Kp, short* __restrict__ U16, short* __restrict__ V16,
    short* __restrict__ w2f16)
{
    __shared__ __attribute__((aligned(16))) char smem[46208];
    const int t = threadIdx.x;
    const int role = blockIdx.x;

    if (role < 96){
        // ---------------- uv role ----------------
        float* Ws = reinterpret_cast<float*>(smem);   // [3][32][32] = 12 KB
        const int yb = role & 15;
        const int cs = (role >> 4) % 3;
        const int uv = role / 48;
        const float* P = uv ? PR : PL;
        short* O = uv ? V16 : U16;
        const int o_lo = (cs == 1) ? 1 : 0;
        const int o_hi = (cs == 2) ? 1 : 2;

        for (int e = t; e < 3072; e += 256){
            int co = e & 31;
            int q  = e >> 5;
            int d  = q >> 5;
            int ci = q & 31;
            float s = 0.f;
            for (int o = o_lo; o <= o_hi; ++o){
                int tap = uv ? (o * 3 + d) : (d * 3 + o);
                s += w1[co * 288 + ci * 9 + tap];
            }
            Ws[q * 32 + co] = s;
        }
        __syncthreads();

        const int co = t & 31;
        const int yi = t >> 5;
        #pragma unroll
        for (int r = 0; r < 8; ++r){
            int y = yb * 64 + r * 8 + yi;
            float acc = 0.f;
            #pragma unroll
            for (int d = 0; d < 3; ++d){
                int row = y - 1 + d;
                if (row >= 0 && row < 1024){
                    const float* pr = P + (size_t)row * 32;
                    const float* ws = Ws + d * 1024 + co;
                    #pragma unroll
                    for (int ci = 0; ci < 32; ++ci)
                        acc = fmaf(pr[ci], ws[ci * 32], acc);
                }
            }
            O[((size_t)cs * 1024 + y) * 32 + co] = f2h_bits(acc);
        }
        return;
    }

    if (role == 97){
        // ---------------- w2pack role ----------------
        for (int e = t; e < 9216; e += 256){
            int co  = e / 288;
            int rem = e - co * 288;
            int ci  = rem / 9;
            int tap = rem - ci * 9;
            w2f16[(tap * 32 + co) * 32 + (ci ^ SWZ(co))] = f2h_bits(w2[e]);
        }
        return;
    }

    // ---------------- cveck role (round-10 version) ----------------
    float* ws_l = reinterpret_cast<float*>(smem);             // 4 KB
    float* ws_r = reinterpret_cast<float*>(smem + 4096);      // 4 KB
    float* red  = reinterpret_cast<float*>(smem + 8192);      // 1 KB
    float* cvs  = reinterpret_cast<float*>(smem + 9216);      // 128 B
    float* w1s  = reinterpret_cast<float*>(smem + 9344);      // 36 KB

    #pragma unroll
    for (int q = 0; q < 9; ++q){
        int idx = (t + q * 256) * 4;
        *reinterpret_cast<float4*>(&w1s[idx]) =
            *reinterpret_cast<const float4*>(w1 + idx);
    }
    for (int j = t; j < 1024; j += 256){
        float sl = 0.f, sr = 0.f;
        #pragma unroll
        for (int b = 0; b < 16; ++b){
            sl += part[b * 1024 + j];
            sr += part[16384 + b * 1024 + j];
        }
        ws_l[j] = sl; ws_r[j] = sr;
    }
    __syncthreads();
    {
        const int h = t & 31;
        const int seg = t >> 5;
        const float* wl = W_hopi + (size_t)h * 2048 + seg * 128;
        const float* wr = wl + 1024;
        float s = 0.f;
        #pragma unroll 8
        for (int j = 0; j < 128; j += 4){
            float4 a = *reinterpret_cast<const float4*>(wl + j);
            float4 b = *reinterpret_cast<const float4*>(wr + j);
            const float* l = &ws_l[seg * 128 + j];
            const float* r = &ws_r[seg * 128 + j];
            s = fmaf(l[0], a.x, s); s = fmaf(l[1], a.y, s);
            s = fmaf(l[2], a.z, s); s = fmaf(l[3], a.w, s);
            s = fmaf(r[0], b.x, s); s = fmaf(r[1], b.y, s);
            s = fmaf(r[2], b.z, s); s = fmaf(r[3], b.w, s);
        }
        red[t] = s;
    }
    __syncthreads();
    if (t < 32){
        float tot = b_hopi[t];
        #pragma unroll
        for (int g = 0; g < 8; ++g) tot += red[g * 32 + t];
        cvs[t] = tot;
    }
    __syncthreads();
    for (int e = t; e < 288; e += 256){
        int co  = e & 31;
        int cse = e >> 5;
        int yc  = cse / 3, xc = cse - yc * 3;
        float sum = b1[co];
        for (int ci = 0; ci < 32; ++ci){
            const float* wp = &w1s[co * 288 + ci * 9];
            float t00 = wp[0], t01 = wp[1], t02 = wp[2];
            float t10 = wp[3], t11 = wp[4], t12 = wp[5];
            float t20 = wp[6], t21 = wp[7], t22 = wp[8];
            float r0, r1, r2;
            if (xc == 0){ r0 = t00+t01+t02; r1 = t10+t11+t12; r2 = t20+t21+t22; }
            else if (xc == 1){ r0 = t01+t02; r1 = t11+t12; r2 = t21+t22; }
            else { r0 = t00+t01; r1 = t10+t11; r2 = t20+t21; }
            float wsum = (yc == 0) ? (r0+r1+r2) : ((yc == 1) ? (r1+r2) : (r0+r1));
            sum = fmaf(cvs[ci], wsum, sum);
        }
        Kp[cse * 32 + co] = sum;
    }
}

// ---------------------------------------------------------------------------
// K3: stage ys = relu(U+V+K'), wB by uint4 copy of prepacked w2f16, then
// conv2+relu+conv3 on f16 MFMA. LDS = 39,168 B. block 512, grid 64x64.
// ---------------------------------------------------------------------------
__global__ __launch_bounds__(512) void conv_kernel(
    const short* __restrict__ U16, const short* __restrict__ V16,
    const float* __restrict__ Kp, const short* __restrict__ w2f16,
    const float* __restrict__ b2,
    const float* __restrict__ w3, const float* __restrict__ b3,
    float* __restrict__ outp)
{
    __shared__ __attribute__((aligned(16))) short ys[18 * 18 * 32];
    __shared__ __attribute__((aligned(16))) short wB[9 * 32 * 32];

    const int t    = threadIdx.x;
    const int oy0  = blockIdx.y * 16;
    const int ox0  = blockIdx.x * 16;
    const int wid  = t >> 6;
    const int lane = t & 63;
    const int lr   = lane & 15;
    const int lg   = lane >> 4;

    // ---- stage wB: plain vector copy of prepacked image (1152 uint4) ----
    {
        const uint4* src = reinterpret_cast<const uint4*>(w2f16);
        uint4* dst = reinterpret_cast<uint4*>(wB);
        #pragma unroll
        for (int e = t; e < 1152; e += 512)
            dst[e] = src[e];
    }
    // ---- stage ys: 324 px x 32 k, y1 = relu(U+V+K') ----
    #pragma unroll
    for (int pass = 0; pass < 6; ++pass){
        int idx = t + pass * 512;
        if (idx < 2592){
            int po  = idx >> 3;
            int cp  = (idx & 7) * 4;
            int ryo = po / 18;
            int rxo = po - ryo * 18;
            int gy = oy0 - 1 + ryo, gx = ox0 - 1 + rxo;
            half4 h = {(_Float16)0.f, (_Float16)0.f, (_Float16)0.f, (_Float16)0.f};
            if ((unsigned)gy < 1024u && (unsigned)gx < 1024u){
                int yc = (gy == 0) ? 1 : ((gy == 1023) ? 2 : 0);
                int xc = (gx == 0) ? 1 : ((gx == 1023) ? 2 : 0);
                half4 u = *reinterpret_cast<const half4*>(
                    &U16[((size_t)(xc << 10) + gy) * 32 + cp]);
                half4 v = *reinterpret_cast<const half4*>(
                    &V16[((size_t)(yc << 10) + gx) * 32 + cp]);
                float4 k = *reinterpret_cast<const float4*>(&Kp[(yc * 3 + xc) * 32 + cp]);
                h[0] = (_Float16)fmaxf((float)u[0] + (float)v[0] + k.x, 0.f);
                h[1] = (_Float16)fmaxf((float)u[1] + (float)v[1] + k.y, 0.f);
                h[2] = (_Float16)fmaxf((float)u[2] + (float)v[2] + k.z, 0.f);
                h[3] = (_Float16)fmaxf((float)u[3] + (float)v[3] + k.w, 0.f);
            }
            *reinterpret_cast<half4*>(&ys[po * 32 + (cp ^ SWZ(rxo))]) = h;
        }
    }
    __syncthreads();

    // ================= conv2 + conv3: 256 outputs =========
    {
        half8 Bf[2][9];
        float bias[2], w3v[2];
        #pragma unroll
        for (int n = 0; n < 2; ++n){
            int co = n * 16 + lr;
            bias[n] = b2[co];
            w3v[n]  = w3[co];
            #pragma unroll
            for (int tap = 0; tap < 9; ++tap)
                Bf[n][tap] = *reinterpret_cast<const half8*>(
                    &wB[(tap * 32 + co) * 32 + ((lg * 8) ^ SWZ(co))]);
        }
        const float b3v = b3[0];
        for (int s = wid; s < 16; s += 8){
            int p  = s * 16 + lr;
            int ry = p >> 4;
            int rx = p & 15;
            f32x4 acc0 = {0.f, 0.f, 0.f, 0.f};
            f32x4 acc1 = {0.f, 0.f, 0.f, 0.f};
            #pragma unroll
            for (int tap = 0; tap < 9; ++tap){
                const int dy = tap / 3, dx = tap - (tap / 3) * 3;
                int pix = (ry + dy) * 18 + rx + dx;
                half8 A = *reinterpret_cast<const half8*>(
                    &ys[pix * 32 + ((lg * 8) ^ SWZ(rx + dx))]);
                acc0 = __builtin_amdgcn_mfma_f32_16x16x32_f16(A, Bf[0][tap], acc0, 0, 0, 0);
                acc1 = __builtin_amdgcn_mfma_f32_16x16x32_f16(A, Bf[1][tap], acc1, 0, 0, 0);
            }
            float part[4];
            #pragma unroll
            for (int j = 0; j < 4; ++j)
                part[j] = w3v[0] * fmaxf(acc0[j] + bias[0], 0.f)
                        + w3v[1] * fmaxf(acc1[j] + bias[1], 0.f);
            #pragma unroll
            for (int m = 1; m < 16; m <<= 1)
                #pragma unroll
                for (int j = 0; j < 4; ++j)
                    part[j] += __shfl_xor(part[j], m);
            if (lr == 0){
                float4 o = make_float4(part[0] + b3v, part[1] + b3v,
                                       part[2] + b3v, part[3] + b3v);
                *reinterpret_cast<float4*>(outp + (size_t)(oy0 + s) * 1024 + ox0 + lg * 4) = o;
            }
        }
    }
}

// ---------------------------------------------------------------------------
extern "C" void kernel_launch(void* const* d_in, const int* in_sizes, int n_in,
                              void* d_out, int out_size, void* d_ws, size_t ws_size,
                              hipStream_t stream)
{
    const float* lig_nf = (const float*)d_in[0];
    const float* lig_ef = (const float*)d_in[1];
    const float* rec_nf = (const float*)d_in[3];
    const float* rec_ef = (const float*)d_in[4];
    const float* Wn     = (const float*)d_in[6];
    const float* bn     = (const float*)d_in[7];
    const float* We     = (const float*)d_in[8];
    const float* be     = (const float*)d_in[9];
    const float* W_hopi = (const float*)d_in[12];
    const float* b_hopi = (const float*)d_in[13];
    const float* w1     = (const float*)d_in[14];
    const float* b1     = (const float*)d_in[15];
    const float* w2     = (const float*)d_in[16];
    const float* b2     = (const float*)d_in[17];
    const float* w3     = (const float*)d_in[18];
    const float* b3     = (const float*)d_in[19];
    float* outp = (float*)d_out;

    float* part  = (float*)d_ws;                              // [2][16][1024] f32
    float* PL    = (float*)((char*)d_ws + 131072);            // 1024*32 f32
    float* PR    = (float*)((char*)d_ws + 262144);            // 1024*32 f32
    float* Kp    = (float*)((char*)d_ws + 393216);            // 3*3*32 f32
    short* U16   = (short*)((char*)d_ws + 394368);            // 3*1024*32 f16
    short* V16   = (short*)((char*)d_ws + 590976);            // 3*1024*32 f16
    short* w2f16 = (short*)((char*)d_ws + 787584);            // 9216 f16 swizzled

    dim3 g1(8, 20, 2);
    gnnproj_kernel<<<g1, 512, 0, stream>>>(lig_nf, lig_ef, rec_nf, rec_ef,
                                           Wn, We, bn, be, W_hopi,
                                           part, PL, PR);
    prep_kernel<<<98, 256, 0, stream>>>(W_hopi, b_hopi, w1, b1, w2,
                                        part, PL, PR, Kp, U16, V16, w2f16);
    dim3 g3(64, 64);
    conv_kernel<<<g3, 512, 0, stream>>>(U16, V16, Kp, w2f16, b2, w3, b3, outp);
}

// Round 12
// 161.895 us; speedup vs baseline: 1.5245x; 1.5245x over previous
//
#include <hip/hip_runtime.h>

// All tensors float32. Math structure exploited:
//  - softmax over axis of size 1 == 1.0 -> attn all-ones, Wa/ba dead.
//  - weighted = row-sum of tanh(agg), broadcast over COLUMNS (N==D quirk).
//  - lig_p = nf@Wl.T + const  ->  x0[h,i,j] = PL[i,h] + PR[j,h] + c[h]
//  - conv1 is LINEAR in rank-structured x0: y1_pre = U[xc][y] + V[yc][x] + K'.
//    conv stages ys = relu(U+V+K'); conv2+conv3 on f16 MFMA.
//  - ROUND-12: round-11 fusion REVERTED (merging proj into gnn dropped VGPR
//    to 40 -> prefetch registers demoted -> latency-bound 163us). gnn/proj
//    separate again (round-10 exact). KEPT from round 11 (counters cleared
//    them): merged prep kernel (cveck+uv+w2pack) and conv's uint4 wB copy.

typedef _Float16 half8 __attribute__((ext_vector_type(8)));
typedef _Float16 half4 __attribute__((ext_vector_type(4)));
typedef float    f32x4 __attribute__((ext_vector_type(4)));

__device__ __forceinline__ short f2h_bits(float f){
    _Float16 h = (_Float16)f;          // RNE
    return __builtin_bit_cast(short, h);
}
__device__ __forceinline__ half8 pack2(const float4& x, const float4& y){
    half8 r;
    r[0] = (_Float16)x.x; r[1] = (_Float16)x.y;
    r[2] = (_Float16)x.z; r[3] = (_Float16)x.w;
    r[4] = (_Float16)y.x; r[5] = (_Float16)y.y;
    r[6] = (_Float16)y.z; r[7] = (_Float16)y.w;
    return r;
}
__device__ __forceinline__ float tanh_fast(float x){
    float e = __expf(2.f * x);
    return 1.f - 2.f / (e + 1.f);
}

// ci-block swizzle for conv LDS tiles (round-4 verified layout)
#define SWZ(c) ((((c) >> 1) & 3) << 3)

// ---------------------------------------------------------------------------
// K1 (MFMA): agg = tanh([nf|ef]@[Wn|We].T + bn + be); per-block row-sums ->
// part[cx][dblk][row]. BM=128, BN=64, BK=64, 512 thr, register prefetch.
// grid (8,16,2). (round-8/10 version, verbatim)
// ---------------------------------------------------------------------------
__global__ __launch_bounds__(512) void gnn_kernel(
    const float* __restrict__ lig_nf, const float* __restrict__ lig_ef,
    const float* __restrict__ rec_nf, const float* __restrict__ rec_ef,
    const float* __restrict__ Wn, const float* __restrict__ We,
    const float* __restrict__ bn, const float* __restrict__ be,
    float* __restrict__ part)   // [2][16][1024]
{
    __shared__ __attribute__((aligned(16))) short As[128 * 64];
    __shared__ __attribute__((aligned(16))) short Bs[64 * 64];
    __shared__ float red[128][2];

    const int t  = threadIdx.x;
    const int cx = blockIdx.z;
    const float* A0 = cx ? rec_nf : lig_nf;
    const float* A1 = cx ? rec_ef : lig_ef;
    const int j0 = blockIdx.x * 128;
    const int d0 = blockIdx.y * 64;

    const int wid  = t >> 6;
    const int wm   = wid >> 1;
    const int wn   = wid & 1;
    const int lane = t & 63;
    const int lr   = lane & 15;
    const int lg   = lane >> 4;

    f32x4 acc[2][2];
    #pragma unroll
    for (int m = 0; m < 2; ++m)
        #pragma unroll
        for (int n = 0; n < 2; ++n)
            acc[m][n] = (f32x4){0.f, 0.f, 0.f, 0.f};

    const int arow = t >> 2;
    const int akc  = (t & 3) * 16;
    const int brow = t >> 3;
    const int bkc  = (t & 7) * 8;

    float4 av[4], bv[2];
    {
        const float* ap = A0 + (size_t)(j0 + arow) * 1024 + akc;
        const float* bp = Wn + (size_t)(d0 + brow) * 1024 + bkc;
        #pragma unroll
        for (int q = 0; q < 4; ++q) av[q] = *reinterpret_cast<const float4*>(ap + q * 4);
        #pragma unroll
        for (int q = 0; q < 2; ++q) bv[q] = *reinterpret_cast<const float4*>(bp + q * 4);
    }

    for (int kb = 0; kb < 2048; kb += 64){
        __syncthreads();
        {
            const int ga = (t & 3) * 2;
            const int sa = arow & 7;
            *reinterpret_cast<half8*>(&As[arow * 64 + ((ga    ) ^ sa) * 8]) = pack2(av[0], av[1]);
            *reinterpret_cast<half8*>(&As[arow * 64 + ((ga + 1) ^ sa) * 8]) = pack2(av[2], av[3]);
            *reinterpret_cast<half8*>(&Bs[brow * 64 + (((t & 7)) ^ (brow & 7)) * 8]) = pack2(bv[0], bv[1]);
        }
        {
            const int kbn = (kb + 64) & 2047;
            const float* Asrc = (kbn < 1024) ? A0 : A1;
            const float* Bsrc = (kbn < 1024) ? Wn : We;
            const int kk = kbn & 1023;
            const float* ap = Asrc + (size_t)(j0 + arow) * 1024 + kk + akc;
            const float* bp = Bsrc + (size_t)(d0 + brow) * 1024 + kk + bkc;
            #pragma unroll
            for (int q = 0; q < 4; ++q) av[q] = *reinterpret_cast<const float4*>(ap + q * 4);
            #pragma unroll
            for (int q = 0; q < 2; ++q) bv[q] = *reinterpret_cast<const float4*>(bp + q * 4);
        }
        __syncthreads();

        #pragma unroll
        for (int ks = 0; ks < 2; ++ks){
            half8 Af[2], Bf[2];
            #pragma unroll
            for (int m = 0; m < 2; ++m){
                int row = wm * 32 + m * 16 + lr;
                int g   = ((ks * 4 + lg) ^ (row & 7)) * 8;
                Af[m] = *reinterpret_cast<const half8*>(&As[row * 64 + g]);
            }
            #pragma unroll
            for (int n = 0; n < 2; ++n){
                int col = wn * 32 + n * 16 + lr;
                int g   = ((ks * 4 + lg) ^ (col & 7)) * 8;
                Bf[n] = *reinterpret_cast<const half8*>(&Bs[col * 64 + g]);
            }
            #pragma unroll
            for (int m = 0; m < 2; ++m)
                #pragma unroll
                for (int n = 0; n < 2; ++n)
                    acc[m][n] = __builtin_amdgcn_mfma_f32_16x16x32_f16(
                        Af[m], Bf[n], acc[m][n], 0, 0, 0);
        }
    }

    float rowsum[2][4];
    #pragma unroll
    for (int m = 0; m < 2; ++m)
        #pragma unroll
        for (int jj = 0; jj < 4; ++jj) rowsum[m][jj] = 0.f;
    #pragma unroll
    for (int n = 0; n < 2; ++n){
        int d = d0 + wn * 32 + n * 16 + lr;
        float bias = bn[d] + be[d];
        #pragma unroll
        for (int m = 0; m < 2; ++m)
            #pragma unroll
            for (int jj = 0; jj < 4; ++jj)
                rowsum[m][jj] += tanh_fast(acc[m][n][jj] + bias);
    }
    #pragma unroll
    for (int mask = 1; mask < 16; mask <<= 1)
        #pragma unroll
        for (int m = 0; m < 2; ++m)
            #pragma unroll
            for (int jj = 0; jj < 4; ++jj)
                rowsum[m][jj] += __shfl_xor(rowsum[m][jj], mask);
    __syncthreads();
    if (lr == 0){
        #pragma unroll
        for (int m = 0; m < 2; ++m)
            #pragma unroll
            for (int jj = 0; jj < 4; ++jj)
                red[wm * 32 + m * 16 + lg * 4 + jj][wn] = rowsum[m][jj];
    }
    __syncthreads();
    if (t < 128)
        part[(size_t)cx * 16384 + (size_t)blockIdx.y * 1024 + j0 + t]
            = red[t][0] + red[t][1];
}

// ---------------------------------------------------------------------------
// K2a: PL[i,h] = sum_j nf[i,j]*Wl[h,j]; PR analog. grid (128,2), block 256
// (round-10 verbatim)
// ---------------------------------------------------------------------------
__global__ __launch_bounds__(256) void proj_kernel(
    const float* __restrict__ lig_nf, const float* __restrict__ rec_nf,
    const float* __restrict__ W_hopi, float* __restrict__ PL, float* __restrict__ PR)
{
    const int t  = threadIdx.x;
    const int cx = blockIdx.y;
    const float* nf = cx ? rec_nf : lig_nf;
    const float* W  = W_hopi + (cx ? 1024 : 0);
    float* outp     = cx ? PR : PL;
    const int h = t & 31;
    const int i = blockIdx.x * 8 + (t >> 5);
    const float* nrow = nf + (size_t)i * 1024;
    const float* wrow = W + (size_t)h * 2048;
    float s0 = 0.f, s1 = 0.f;
    #pragma unroll 4
    for (int j = 0; j < 1024; j += 8){
        float4 a0 = *reinterpret_cast<const float4*>(nrow + j);
        float4 b0 = *reinterpret_cast<const float4*>(wrow + j);
        float4 a1 = *reinterpret_cast<const float4*>(nrow + j + 4);
        float4 b1 = *reinterpret_cast<const float4*>(wrow + j + 4);
        s0 = fmaf(a0.x, b0.x, s0); s0 = fmaf(a0.y, b0.y, s0);
        s0 = fmaf(a0.z, b0.z, s0); s0 = fmaf(a0.w, b0.w, s0);
        s1 = fmaf(a1.x, b1.x, s1); s1 = fmaf(a1.y, b1.y, s1);
        s1 = fmaf(a1.z, b1.z, s1); s1 = fmaf(a1.w, b1.w, s1);
    }
    outp[(size_t)i * 32 + h] = s0 + s1;
}

// ---------------------------------------------------------------------------
// K2b: merged prep (round-11 version, counters cleared it). grid 98 x 256.
//  blocks 0..95 : uv ; block 96: cveck ; block 97: w2pack
// ---------------------------------------------------------------------------
__global__ __launch_bounds__(256) void prep_kernel(
    const float* __restrict__ W_hopi, const float* __restrict__ b_hopi,
    const float* __restrict__ w1, const float* __restrict__ b1,
    const float* __restrict__ w2,
    const float* __restrict__ part,
    const float* __restrict__ PL, const float* __restrict__ PR,
    float* __restrict__ Kp, short* __restrict__ U16, short* __restrict__ V16,
    short* __restrict__ w2f16)
{
    __shared__ __attribute__((aligned(16))) char smem[46208];
    const int t = threadIdx.x;
    const int role = blockIdx.x;

    if (role < 96){
        float* Ws = reinterpret_cast<float*>(smem);   // [3][32][32]
        const int yb = role & 15;
        const int cs = (role >> 4) % 3;
        const int uv = role / 48;
        const float* P = uv ? PR : PL;
        short* O = uv ? V16 : U16;
        const int o_lo = (cs == 1) ? 1 : 0;
        const int o_hi = (cs == 2) ? 1 : 2;

        for (int e = t; e < 3072; e += 256){
            int co = e & 31;
            int q  = e >> 5;
            int d  = q >> 5;
            int ci = q & 31;
            float s = 0.f;
            for (int o = o_lo; o <= o_hi; ++o){
                int tap = uv ? (o * 3 + d) : (d * 3 + o);
                s += w1[co * 288 + ci * 9 + tap];
            }
            Ws[q * 32 + co] = s;
        }
        __syncthreads();

        const int co = t & 31;
        const int yi = t >> 5;
        #pragma unroll
        for (int r = 0; r < 8; ++r){
            int y = yb * 64 + r * 8 + yi;
            float acc = 0.f;
            #pragma unroll
            for (int d = 0; d < 3; ++d){
                int row = y - 1 + d;
                if (row >= 0 && row < 1024){
                    const float* pr = P + (size_t)row * 32;
                    const float* ws = Ws + d * 1024 + co;
                    #pragma unroll
                    for (int ci = 0; ci < 32; ++ci)
                        acc = fmaf(pr[ci], ws[ci * 32], acc);
                }
            }
            O[((size_t)cs * 1024 + y) * 32 + co] = f2h_bits(acc);
        }
        return;
    }

    if (role == 97){
        for (int e = t; e < 9216; e += 256){
            int co  = e / 288;
            int rem = e - co * 288;
            int ci  = rem / 9;
            int tap = rem - ci * 9;
            w2f16[(tap * 32 + co) * 32 + (ci ^ SWZ(co))] = f2h_bits(w2[e]);
        }
        return;
    }

    // cveck role
    float* ws_l = reinterpret_cast<float*>(smem);
    float* ws_r = reinterpret_cast<float*>(smem + 4096);
    float* red  = reinterpret_cast<float*>(smem + 8192);
    float* cvs  = reinterpret_cast<float*>(smem + 9216);
    float* w1s  = reinterpret_cast<float*>(smem + 9344);

    #pragma unroll
    for (int q = 0; q < 9; ++q){
        int idx = (t + q * 256) * 4;
        *reinterpret_cast<float4*>(&w1s[idx]) =
            *reinterpret_cast<const float4*>(w1 + idx);
    }
    for (int j = t; j < 1024; j += 256){
        float sl = 0.f, sr = 0.f;
        #pragma unroll
        for (int b = 0; b < 16; ++b){
            sl += part[b * 1024 + j];
            sr += part[16384 + b * 1024 + j];
        }
        ws_l[j] = sl; ws_r[j] = sr;
    }
    __syncthreads();
    {
        const int h = t & 31;
        const int seg = t >> 5;
        const float* wl = W_hopi + (size_t)h * 2048 + seg * 128;
        const float* wr = wl + 1024;
        float s = 0.f;
        #pragma unroll 8
        for (int j = 0; j < 128; j += 4){
            float4 a = *reinterpret_cast<const float4*>(wl + j);
            float4 b = *reinterpret_cast<const float4*>(wr + j);
            const float* l = &ws_l[seg * 128 + j];
            const float* r = &ws_r[seg * 128 + j];
            s = fmaf(l[0], a.x, s); s = fmaf(l[1], a.y, s);
            s = fmaf(l[2], a.z, s); s = fmaf(l[3], a.w, s);
            s = fmaf(r[0], b.x, s); s = fmaf(r[1], b.y, s);
            s = fmaf(r[2], b.z, s); s = fmaf(r[3], b.w, s);
        }
        red[t] = s;
    }
    __syncthreads();
    if (t < 32){
        float tot = b_hopi[t];
        #pragma unroll
        for (int g = 0; g < 8; ++g) tot += red[g * 32 + t];
        cvs[t] = tot;
    }
    __syncthreads();
    for (int e = t; e < 288; e += 256){
        int co  = e & 31;
        int cse = e >> 5;
        int yc  = cse / 3, xc = cse - yc * 3;
        float sum = b1[co];
        for (int ci = 0; ci < 32; ++ci){
            const float* wp = &w1s[co * 288 + ci * 9];
            float t00 = wp[0], t01 = wp[1], t02 = wp[2];
            float t10 = wp[3], t11 = wp[4], t12 = wp[5];
            float t20 = wp[6], t21 = wp[7], t22 = wp[8];
            float r0, r1, r2;
            if (xc == 0){ r0 = t00+t01+t02; r1 = t10+t11+t12; r2 = t20+t21+t22; }
            else if (xc == 1){ r0 = t01+t02; r1 = t11+t12; r2 = t21+t22; }
            else { r0 = t00+t01; r1 = t10+t11; r2 = t20+t21; }
            float wsum = (yc == 0) ? (r0+r1+r2) : ((yc == 1) ? (r1+r2) : (r0+r1));
            sum = fmaf(cvs[ci], wsum, sum);
        }
        Kp[cse * 32 + co] = sum;
    }
}

// ---------------------------------------------------------------------------
// K3: stage ys = relu(U+V+K'), wB by uint4 copy of prepacked w2f16, then
// conv2+relu+conv3 on f16 MFMA. LDS = 39,168 B. block 512, grid 64x64.
// ---------------------------------------------------------------------------
__global__ __launch_bounds__(512) void conv_kernel(
    const short* __restrict__ U16, const short* __restrict__ V16,
    const float* __restrict__ Kp, const short* __restrict__ w2f16,
    const float* __restrict__ b2,
    const float* __restrict__ w3, const float* __restrict__ b3,
    float* __restrict__ outp)
{
    __shared__ __attribute__((aligned(16))) short ys[18 * 18 * 32];
    __shared__ __attribute__((aligned(16))) short wB[9 * 32 * 32];

    const int t    = threadIdx.x;
    const int oy0  = blockIdx.y * 16;
    const int ox0  = blockIdx.x * 16;
    const int wid  = t >> 6;
    const int lane = t & 63;
    const int lr   = lane & 15;
    const int lg   = lane >> 4;

    {
        const uint4* src = reinterpret_cast<const uint4*>(w2f16);
        uint4* dst = reinterpret_cast<uint4*>(wB);
        #pragma unroll
        for (int e = t; e < 1152; e += 512)
            dst[e] = src[e];
    }
    #pragma unroll
    for (int pass = 0; pass < 6; ++pass){
        int idx = t + pass * 512;
        if (idx < 2592){
            int po  = idx >> 3;
            int cp  = (idx & 7) * 4;
            int ryo = po / 18;
            int rxo = po - ryo * 18;
            int gy = oy0 - 1 + ryo, gx = ox0 - 1 + rxo;
            half4 h = {(_Float16)0.f, (_Float16)0.f, (_Float16)0.f, (_Float16)0.f};
            if ((unsigned)gy < 1024u && (unsigned)gx < 1024u){
                int yc = (gy == 0) ? 1 : ((gy == 1023) ? 2 : 0);
                int xc = (gx == 0) ? 1 : ((gx == 1023) ? 2 : 0);
                half4 u = *reinterpret_cast<const half4*>(
                    &U16[((size_t)(xc << 10) + gy) * 32 + cp]);
                half4 v = *reinterpret_cast<const half4*>(
                    &V16[((size_t)(yc << 10) + gx) * 32 + cp]);
                float4 k = *reinterpret_cast<const float4*>(&Kp[(yc * 3 + xc) * 32 + cp]);
                h[0] = (_Float16)fmaxf((float)u[0] + (float)v[0] + k.x, 0.f);
                h[1] = (_Float16)fmaxf((float)u[1] + (float)v[1] + k.y, 0.f);
                h[2] = (_Float16)fmaxf((float)u[2] + (float)v[2] + k.z, 0.f);
                h[3] = (_Float16)fmaxf((float)u[3] + (float)v[3] + k.w, 0.f);
            }
            *reinterpret_cast<half4*>(&ys[po * 32 + (cp ^ SWZ(rxo))]) = h;
        }
    }
    __syncthreads();

    {
        half8 Bf[2][9];
        float bias[2], w3v[2];
        #pragma unroll
        for (int n = 0; n < 2; ++n){
            int co = n * 16 + lr;
            bias[n] = b2[co];
            w3v[n]  = w3[co];
            #pragma unroll
            for (int tap = 0; tap < 9; ++tap)
                Bf[n][tap] = *reinterpret_cast<const half8*>(
                    &wB[(tap * 32 + co) * 32 + ((lg * 8) ^ SWZ(co))]);
        }
        const float b3v = b3[0];
        for (int s = wid; s < 16; s += 8){
            int p  = s * 16 + lr;
            int ry = p >> 4;
            int rx = p & 15;
            f32x4 acc0 = {0.f, 0.f, 0.f, 0.f};
            f32x4 acc1 = {0.f, 0.f, 0.f, 0.f};
            #pragma unroll
            for (int tap = 0; tap < 9; ++tap){
                const int dy = tap / 3, dx = tap - (tap / 3) * 3;
                int pix = (ry + dy) * 18 + rx + dx;
                half8 A = *reinterpret_cast<const half8*>(
                    &ys[pix * 32 + ((lg * 8) ^ SWZ(rx + dx))]);
                acc0 = __builtin_amdgcn_mfma_f32_16x16x32_f16(A, Bf[0][tap], acc0, 0, 0, 0);
                acc1 = __builtin_amdgcn_mfma_f32_16x16x32_f16(A, Bf[1][tap], acc1, 0, 0, 0);
            }
            float part[4];
            #pragma unroll
            for (int j = 0; j < 4; ++j)
                part[j] = w3v[0] * fmaxf(acc0[j] + bias[0], 0.f)
                        + w3v[1] * fmaxf(acc1[j] + bias[1], 0.f);
            #pragma unroll
            for (int m = 1; m < 16; m <<= 1)
                #pragma unroll
                for (int j = 0; j < 4; ++j)
                    part[j] += __shfl_xor(part[j], m);
            if (lr == 0){
                float4 o = make_float4(part[0] + b3v, part[1] + b3v,
                                       part[2] + b3v, part[3] + b3v);
                *reinterpret_cast<float4*>(outp + (size_t)(oy0 + s) * 1024 + ox0 + lg * 4) = o;
            }
        }
    }
}

// ---------------------------------------------------------------------------
extern "C" void kernel_launch(void* const* d_in, const int* in_sizes, int n_in,
                              void* d_out, int out_size, void* d_ws, size_t ws_size,
                              hipStream_t stream)
{
    const float* lig_nf = (const float*)d_in[0];
    const float* lig_ef = (const float*)d_in[1];
    const float* rec_nf = (const float*)d_in[3];
    const float* rec_ef = (const float*)d_in[4];
    const float* Wn     = (const float*)d_in[6];
    const float* bn     = (const float*)d_in[7];
    const float* We     = (const float*)d_in[8];
    const float* be     = (const float*)d_in[9];
    const float* W_hopi = (const float*)d_in[12];
    const float* b_hopi = (const float*)d_in[13];
    const float* w1     = (const float*)d_in[14];
    const float* b1     = (const float*)d_in[15];
    const float* w2     = (const float*)d_in[16];
    const float* b2     = (const float*)d_in[17];
    const float* w3     = (const float*)d_in[18];
    const float* b3     = (const float*)d_in[19];
    float* outp = (float*)d_out;

    float* part  = (float*)d_ws;                              // [2][16][1024] f32
    float* PL    = (float*)((char*)d_ws + 131072);            // 1024*32 f32
    float* PR    = (float*)((char*)d_ws + 262144);            // 1024*32 f32
    float* Kp    = (float*)((char*)d_ws + 393216);            // 3*3*32 f32
    short* U16   = (short*)((char*)d_ws + 394368);            // 3*1024*32 f16
    short* V16   = (short*)((char*)d_ws + 590976);            // 3*1024*32 f16
    short* w2f16 = (short*)((char*)d_ws + 787584);            // 9216 f16 swizzled

    dim3 g1(8, 16, 2);
    gnn_kernel<<<g1, 512, 0, stream>>>(lig_nf, lig_ef, rec_nf, rec_ef,
                                       Wn, We, bn, be, part);
    dim3 g2(128, 2);
    proj_kernel<<<g2, 256, 0, stream>>>(lig_nf, rec_nf, W_hopi, PL, PR);
    prep_kernel<<<98, 256, 0, stream>>>(W_hopi, b_hopi, w1, b1, w2,
                                        part, PL, PR, Kp, U16, V16, w2f16);
    dim3 g3(64, 64);
    conv_kernel<<<g3, 512, 0, stream>>>(U16, V16, Kp, w2f16, b2, w3, b3, outp);
}